// Round 7
// baseline (38.326 us; speedup 1.0000x reference)
//
#include <hip/hip_runtime.h>
#include <math.h>

#define K_CENTERS 512
#define NTHREADS 512
#define CELLS 1024
#define CLIM 1.002f
#define CHEB_D 64                  /* degree; CHEB_D+1 points & coeffs */
#define XC 5.5f                    /* Chebyshev domain [-XC, XC] */
#define PI_F 3.14159265358979f

__device__ __forceinline__ bool pl_less(float2 A, float2 B) {
    return (A.x < B.x) || (A.x == B.x && A.y < B.y);
}

// Single dispatch, zero cross-block communication. 256 blocks x 512 threads
// (1 block/CU): each block redundantly builds (a) value-sorted (center,origIdx)
// pairs via bitonic sort in LDS, (b) a 1025-entry insertion-count table via
// binary search, (c) a degree-64 Chebyshev model of softout(x) on [-XC,XC]
// (65 exact point evals over all 512 centers + DCT-I). Then 4 elems/thread:
// Clenshaw softout; exact f32-faithful argmin via candidate scan of sorted
// neighbors (reference d=x-c, d2=d*d rounding, first-min tie-break on orig
// index). Outputs (concat): zbar(=hardout), softout, hardout, symbols(float).
__global__ __launch_bounds__(NTHREADS, 2) void fused_k(const float* __restrict__ data,
                                                       const float* __restrict__ centers,
                                                       float* __restrict__ out, int N) {
    __shared__ float2 sp[K_CENTERS];     // sorted {value, (float)origIdx}
    __shared__ float  cnt[CELLS + 1];    // insertion counts at cell edges
    __shared__ float  fp[CHEB_D + 1];    // softout at cheb points
    __shared__ float  cf[CHEB_D + 1];    // cheb coeffs (ends pre-halved)
    int t = threadIdx.x;

    int base = (blockIdx.x * NTHREADS + t) * 4;
    float4 xv = make_float4(0.f, 0.f, 0.f, 0.f);
    if (base < N) xv = *reinterpret_cast<const float4*>(data + base);  // prefetch under setup

    // ---- load centers ----
    if (t < K_CENTERS) sp[t] = make_float2(centers[t], (float)t);
    __syncthreads();

    // ---- bitonic sort of 512 pairs, key (value, origIdx) ascending ----
    for (int k = 2; k <= K_CENTERS; k <<= 1) {
        for (int j = k >> 1; j >= 1; j >>= 1) {
            if (t < 256) {
                int i  = ((t & ~(j - 1)) << 1) | (t & (j - 1));
                int ip = i | j;
                bool asc = (i & k) == 0;
                float2 P = sp[i], Q = sp[ip];
                bool sw = asc ? pl_less(Q, P) : pl_less(P, Q);
                if (sw) { sp[i] = Q; sp[ip] = P; }
            }
            __syncthreads();
        }
    }

    // ---- cnt table: cnt[m] = #{c < L_m}, L_m = -CLIM + m*step ----
    const float step = (2.0f * CLIM) / (float)CELLS;
    for (int m = t; m <= CELLS; m += NTHREADS) {
        float L = fmaf((float)m, step, -CLIM);
        int lo = 0, hi = K_CENTERS;
#pragma unroll
        for (int it = 0; it < 9; ++it) {          // 2^9 = 512
            int mid = (lo + hi) >> 1;
            if (sp[mid].x < L) lo = mid + 1; else hi = mid;
        }
        cnt[m] = (float)lo;
    }

    // ---- Chebyshev point values: fp[p] = softout(XC*cos(pi*p/D)) ----
    if (t < 2 * (CHEB_D + 1)) {
        int p = t >> 1, s = t & 1;
        float xp = XC * __cosf((float)p * (PI_F / (float)CHEB_D));
        float w = 0.f, wc = 0.f;
        int k0 = s * 256;
        for (int q = 0; q < 256; ++q) {
            float cv = centers[k0 + q];
            float d = xp - cv;
            float e = __expf(-d * d);             // SIGMA = 1
            w += e;
            wc = fmaf(e, cv, wc);
        }
        w += __shfl_xor(w, 1);  wc += __shfl_xor(wc, 1);
        if (s == 0) fp[p] = wc / w;
    }
    __syncthreads();

    // ---- DCT-I coefficients: a_j = (2/D) * sum'' fp[p] cos(pi*j*p/D) ----
    if (t <= CHEB_D) {
        int j = t;
        float acc = 0.f;
        for (int p = 0; p <= CHEB_D; ++p) {
            float wgt = (p == 0 || p == CHEB_D) ? 0.5f : 1.0f;
            int m = (j * p) & 127;                // cos period 2*pi = 128 steps
            acc = fmaf(wgt * fp[p], cosf((float)m * (PI_F / 64.0f)), acc);
        }
        float aj = acc * (2.0f / (float)CHEB_D);
        if (j == 0 || j == CHEB_D) aj *= 0.5f;    // fold sum'' convention
        cf[j] = aj;
    }
    __syncthreads();

    // ---- phase 2: 4 elements/thread ----
    if (base >= N) return;
    float xs[4] = {xv.x, xv.y, xv.z, xv.w};
    float zb[4], so[4], sy[4];

    // Clenshaw with 4-way ILP (all indices static after unroll)
    float y[4], y2[4], b1[4], b2[4];
#pragma unroll
    for (int e = 0; e < 4; ++e) {
        y[e] = fminf(fmaxf(xs[e] * (1.0f / XC), -1.0f), 1.0f);
        y2[e] = 2.0f * y[e];
        b1[e] = 0.f; b2[e] = 0.f;
    }
    for (int k = CHEB_D; k >= 1; --k) {
        float ck = cf[k];                          // LDS broadcast
#pragma unroll
        for (int e = 0; e < 4; ++e) {
            float bb = fmaf(y2[e], b1[e], ck - b2[e]);
            b2[e] = b1[e]; b1[e] = bb;
        }
    }
    float c0 = cf[0];
#pragma unroll
    for (int e = 0; e < 4; ++e) so[e] = fmaf(y[e], b1[e], c0 - b2[e]);

    const float invstep = (float)CELLS / (2.0f * CLIM);
#pragma unroll
    for (int e = 0; e < 4; ++e) {
        float x = xs[e];
        int n = (int)floorf((x + CLIM) * invstep);
        n = min(max(n, 0), CELLS - 1);
        int jlo = max((int)cnt[n] - 3, 0);
        int jhi = min((int)cnt[n + 1] + 2, K_CENTERS - 1);
        float bd2 = 3.4e38f;
        float bfo = 1.0e9f;       // original index as float (exact for <512)
        float bc = 0.f;
        for (int j = jlo; j <= jhi; ++j) {
            float2 P = sp[j];
            float d = x - P.x;        // same rounding as reference
            float d2 = d * d;         // same rounding as reference
            bool better = (d2 < bd2) || ((d2 == bd2) && (P.y < bfo));
            if (better) { bd2 = d2; bfo = P.y; bc = P.x; }
        }
        zb[e] = bc;                   // zbar forward value == hardout
        sy[e] = bfo;
    }

    *reinterpret_cast<float4*>(out + base)         = make_float4(zb[0], zb[1], zb[2], zb[3]);
    *reinterpret_cast<float4*>(out + N + base)     = make_float4(so[0], so[1], so[2], so[3]);
    *reinterpret_cast<float4*>(out + 2 * N + base) = make_float4(zb[0], zb[1], zb[2], zb[3]);
    *reinterpret_cast<float4*>(out + 3 * N + base) = make_float4(sy[0], sy[1], sy[2], sy[3]);
}

extern "C" void kernel_launch(void* const* d_in, const int* in_sizes, int n_in,
                              void* d_out, int out_size, void* d_ws, size_t ws_size,
                              hipStream_t stream) {
    const float* data    = (const float*)d_in[0];
    const float* centers = (const float*)d_in[1];
    float* out = (float*)d_out;
    int N = in_sizes[0];   // 524288 == 256 * 512 * 4

    int blocks = (N / 4 + NTHREADS - 1) / NTHREADS;   // 256
    fused_k<<<blocks, NTHREADS, 0, stream>>>(data, centers, out, N);
}

// Round 8
// 18.938 us; speedup vs baseline: 2.0238x; 2.0238x over previous
//
#include <hip/hip_runtime.h>
#include <math.h>

#define K_CENTERS 512
#define NTHREADS 512
#define CELLS 1024
#define CLIM 1.002f
#define CHEB_N 64                  /* points; degree CHEB_N-1 = 63 */
#define XC 5.5f                    /* Chebyshev domain [-XC, XC] */
#define PI_F 3.14159265358979f

__device__ __forceinline__ bool pl_less(float2 A, float2 B) {
    return (A.x < B.x) || (A.x == B.x && A.y < B.y);
}

// Single dispatch, zero cross-block communication. 256 blocks x 512 threads
// (1 block/CU), each block redundantly builds its setup in ~9 barriers:
//  - counting sort of 512 (center,origIdx) pairs into value order: LDS
//    histogram over the same 1024-cell grid the scan uses, wave-shfl prefix
//    scan (which IS the cnt[] insertion-count table), atomic-cursor scatter,
//    per-bucket insertion sorts (buckets <= ~5 elems).
//  - degree-63 Chebyshev model of softout(x) on [-XC,XC]: 64 points x 8
//    segments = 512 threads eval exact softmax-mean, DCT-I via __cosf with
//    incremental range-reduced angle.
// Phase 2 (4 elems/thread): Clenshaw softout; exact f32-faithful argmin via
// candidate scan of sorted neighbors (reference d=x-c, d2=d*d rounding,
// first-min tie-break on orig index).
// Outputs (concat): zbar(=hardout), softout, hardout, symbols(as float).
__global__ __launch_bounds__(NTHREADS, 1) void fused_k(const float* __restrict__ data,
                                                       const float* __restrict__ centers,
                                                       float* __restrict__ out, int N) {
    __shared__ float2 sp[K_CENTERS];       // sorted {value, (float)origIdx}
    __shared__ float  vals[K_CENTERS + 8]; // sorted values, padded idx k+(k>>6)
    __shared__ float  cnt[CELLS + 1];      // insertion counts at cell edges (float)
    __shared__ int    istart[CELLS + 1];   // same, int (bucket starts)
    __shared__ int    hist[CELLS];
    __shared__ int    ioff[CELLS];
    __shared__ int    wsum[8], woff[8];
    __shared__ float  fp[CHEB_N];          // softout at cheb points
    __shared__ float  cf[CHEB_N];          // cheb coeffs (ends pre-halved)
    int t = threadIdx.x;
    int lane = t & 63, w = t >> 6;

    int base = (blockIdx.x * NTHREADS + t) * 4;
    float4 xv = make_float4(0.f, 0.f, 0.f, 0.f);
    if (base < N) xv = *reinterpret_cast<const float4*>(data + base);  // prefetch under setup

    const float invstep = (float)CELLS / (2.0f * CLIM);

    // ---- step 1: zero hist/ioff, load my center ----
    hist[t] = 0; hist[t + 512] = 0;
    ioff[t] = 0; ioff[t + 512] = 0;
    float cv = centers[t];
    int bkt = (int)((cv + CLIM) * invstep);     // cv+CLIM > 0: trunc == floor
    bkt = min(max(bkt, 0), CELLS - 1);
    __syncthreads();

    // ---- step 2: histogram ----
    atomicAdd(&hist[bkt], 1);
    __syncthreads();

    // ---- step 3: prefix scan over 1024 buckets (2 per thread) ----
    int h0 = hist[2 * t], h1 = hist[2 * t + 1];
    int pairsum = h0 + h1;
    int incl = pairsum;
#pragma unroll
    for (int off = 1; off < 64; off <<= 1) {
        int v = __shfl_up(incl, off);
        if (lane >= off) incl += v;
    }
    if (lane == 63) wsum[w] = incl;
    __syncthreads();
    if (t < 8) {
        int e = 0;
        for (int k = 0; k < t; ++k) e += wsum[k];
        woff[t] = e;
    }
    __syncthreads();
    {
        int excl = incl - pairsum + woff[w];
        istart[2 * t] = excl;          cnt[2 * t] = (float)excl;
        int mid = excl + h0;
        istart[2 * t + 1] = mid;       cnt[2 * t + 1] = (float)mid;
        if (t == NTHREADS - 1) { istart[CELLS] = K_CENTERS; cnt[CELLS] = (float)K_CENTERS; }
    }
    __syncthreads();

    // ---- step 4: scatter (unordered within bucket) ----
    {
        int pos = istart[bkt] + atomicAdd(&ioff[bkt], 1);
        sp[pos] = make_float2(cv, (float)t);
    }
    __syncthreads();

    // ---- step 5: per-bucket insertion sort (strict total order (value,idx)) ----
    for (int bb = 0; bb < 2; ++bb) {
        int b = 2 * t + bb;
        int s0 = istart[b], s1 = istart[b + 1];
        for (int i = s0 + 1; i < s1; ++i) {
            float2 key = sp[i];
            int j = i - 1;
            while (j >= s0 && pl_less(key, sp[j])) { sp[j + 1] = sp[j]; --j; }
            sp[j + 1] = key;
        }
    }
    __syncthreads();

    // ---- step 6: padded value array (bank-conflict-free segment reads) ----
    vals[t + (t >> 6)] = sp[t].x;
    __syncthreads();

    // ---- step 7: Chebyshev point values fp[p], p = t>>3, 8 segs of 64 ----
    {
        int p = t >> 3, s8 = t & 7;
        float xp = XC * __cosf((float)p * (PI_F / 63.0f));
        float ww = 0.f, wc = 0.f;
        int k0 = s8 * 64;
#pragma unroll 8
        for (int q = 0; q < 64; ++q) {
            int k = k0 + q;
            float cvq = vals[k + (k >> 6)];
            float d = xp - cvq;
            float e = __expf(-d * d);              // SIGMA = 1
            ww += e;
            wc = fmaf(e, cvq, wc);
        }
        ww += __shfl_xor(ww, 1); wc += __shfl_xor(wc, 1);
        ww += __shfl_xor(ww, 2); wc += __shfl_xor(wc, 2);
        ww += __shfl_xor(ww, 4); wc += __shfl_xor(wc, 4);
        if (s8 == 0) fp[p] = wc / ww;
    }
    __syncthreads();

    // ---- step 8: DCT-I coefficients (64 threads, incremental angle) ----
    if (t < CHEB_N) {
        int j = t;
        float acc = 0.f;
        int m = 0;
        for (int p = 0; p < CHEB_N; ++p) {
            float wgt = (p == 0 || p == CHEB_N - 1) ? 0.5f : 1.0f;
            acc = fmaf(wgt * fp[p], __cosf((float)m * (PI_F / 63.0f)), acc);
            m += j; if (m >= 126) m -= 126;        // angle stays in [0, 2pi)
        }
        float aj = acc * (2.0f / 63.0f);
        if (j == 0 || j == CHEB_N - 1) aj *= 0.5f; // fold sum'' convention
        cf[j] = aj;
    }
    __syncthreads();

    // ---- phase 2: 4 elements/thread ----
    if (base >= N) return;
    float xs[4] = {xv.x, xv.y, xv.z, xv.w};
    float zb[4], so[4], sy[4];

    float y[4], y2[4], b1[4], b2[4];
#pragma unroll
    for (int e = 0; e < 4; ++e) {
        y[e] = fminf(fmaxf(xs[e] * (1.0f / XC), -1.0f), 1.0f);
        y2[e] = 2.0f * y[e];
        b1[e] = 0.f; b2[e] = 0.f;
    }
    for (int k = CHEB_N - 1; k >= 1; --k) {
        float ck = cf[k];                           // LDS broadcast
#pragma unroll
        for (int e = 0; e < 4; ++e) {
            float bb = fmaf(y2[e], b1[e], ck - b2[e]);
            b2[e] = b1[e]; b1[e] = bb;
        }
    }
    float c0 = cf[0];
#pragma unroll
    for (int e = 0; e < 4; ++e) so[e] = fmaf(y[e], b1[e], c0 - b2[e]);

#pragma unroll
    for (int e = 0; e < 4; ++e) {
        float x = xs[e];
        int n = (int)floorf((x + CLIM) * invstep);
        n = min(max(n, 0), CELLS - 1);
        int jlo = max((int)cnt[n] - 3, 0);
        int jhi = min((int)cnt[n + 1] + 2, K_CENTERS - 1);
        float bd2 = 3.4e38f;
        float bfo = 1.0e9f;       // original index as float (exact for <512)
        float bc = 0.f;
        for (int j = jlo; j <= jhi; ++j) {
            float2 P = sp[j];
            float d = x - P.x;        // same rounding as reference
            float d2 = d * d;         // same rounding as reference
            bool better = (d2 < bd2) || ((d2 == bd2) && (P.y < bfo));
            if (better) { bd2 = d2; bfo = P.y; bc = P.x; }
        }
        zb[e] = bc;                   // zbar forward value == hardout
        sy[e] = bfo;
    }

    *reinterpret_cast<float4*>(out + base)         = make_float4(zb[0], zb[1], zb[2], zb[3]);
    *reinterpret_cast<float4*>(out + N + base)     = make_float4(so[0], so[1], so[2], so[3]);
    *reinterpret_cast<float4*>(out + 2 * N + base) = make_float4(zb[0], zb[1], zb[2], zb[3]);
    *reinterpret_cast<float4*>(out + 3 * N + base) = make_float4(sy[0], sy[1], sy[2], sy[3]);
}

extern "C" void kernel_launch(void* const* d_in, const int* in_sizes, int n_in,
                              void* d_out, int out_size, void* d_ws, size_t ws_size,
                              hipStream_t stream) {
    const float* data    = (const float*)d_in[0];
    const float* centers = (const float*)d_in[1];
    float* out = (float*)d_out;
    int N = in_sizes[0];   // 524288 == 256 * 512 * 4

    int blocks = (N / 4 + NTHREADS - 1) / NTHREADS;   // 256
    fused_k<<<blocks, NTHREADS, 0, stream>>>(data, centers, out, N);
}

// Round 9
// 17.738 us; speedup vs baseline: 2.1607x; 1.0676x over previous
//
#include <hip/hip_runtime.h>
#include <math.h>

#define K_CENTERS 512
#define NTHREADS 256
#define CELLS 1024
#define CLIM 1.002f
#define CHEB_N 32                  /* points; degree 31 */
#define XC 5.5f                    /* Chebyshev domain [-XC, XC] */
#define PI_F 3.14159265358979f

__device__ __forceinline__ bool pl_less(float2 A, float2 B) {
    return (A.x < B.x) || (A.x == B.x && A.y < B.y);
}

// Single dispatch, zero cross-block communication. 1024 blocks x 256 threads
// (4 blocks/CU, 16 waves/CU -> barrier/latency stalls of one block hide under
// the other three). Each block redundantly builds:
//  - counting sort of 512 (center,origIdx) pairs: LDS histogram over the same
//    1024-cell grid the scan uses, wave-shfl prefix scan (which IS the cnt[]
//    insertion-count table), atomic-cursor scatter, per-bucket insertion sort.
//  - degree-31 Chebyshev model of softout(x) on [-XC,XC]: 32 points x 8
//    segments = 256 threads eval exact softmax-mean, then DCT-I (validated
//    convention from R7/R8, just N=64->32).
// Phase 2 (2 elems/thread): fully-unrolled Clenshaw softout; exact
// f32-faithful argmin via candidate scan of sorted neighbors (reference
// d=x-c, d2=d*d rounding, first-min tie-break on original index).
// Outputs (concat): zbar(=hardout), softout, hardout, symbols(as float).
__global__ __launch_bounds__(NTHREADS, 4) void fused_k(const float* __restrict__ data,
                                                       const float* __restrict__ centers,
                                                       float* __restrict__ out, int N) {
    __shared__ float2 sp[K_CENTERS];       // sorted {value, (float)origIdx}
    __shared__ float  vals[K_CENTERS + 8]; // sorted values, padded idx k+(k>>6)
    __shared__ float  cnt[CELLS + 1];      // insertion counts at cell edges
    __shared__ int    istart[CELLS + 1];   // bucket starts
    __shared__ int    hist[CELLS];
    __shared__ int    ioff[CELLS];
    __shared__ int    wsum[4];
    __shared__ float  fp[CHEB_N];          // softout at cheb points
    __shared__ float  cf[CHEB_N];          // cheb coeffs (ends pre-halved)
    int t = threadIdx.x;
    int lane = t & 63, w = t >> 6;         // 4 waves

    int base = (blockIdx.x * NTHREADS + t) * 2;   // exact fit: no bounds checks
    float2 xv = *reinterpret_cast<const float2*>(data + base);  // prefetch under setup

    const float invstep = (float)CELLS / (2.0f * CLIM);

    // ---- step 1: zero hist/ioff, load 2 centers ----
    hist[t] = 0; hist[t + 256] = 0; hist[t + 512] = 0; hist[t + 768] = 0;
    ioff[t] = 0; ioff[t + 256] = 0; ioff[t + 512] = 0; ioff[t + 768] = 0;
    float cv0 = centers[t], cv1 = centers[t + 256];
    int b0 = min(max((int)((cv0 + CLIM) * invstep), 0), CELLS - 1);
    int b1 = min(max((int)((cv1 + CLIM) * invstep), 0), CELLS - 1);
    __syncthreads();

    // ---- step 2: histogram ----
    atomicAdd(&hist[b0], 1);
    atomicAdd(&hist[b1], 1);
    __syncthreads();

    // ---- step 3: prefix scan over 1024 buckets (4 per thread) ----
    int h0 = hist[4 * t], h1 = hist[4 * t + 1], h2 = hist[4 * t + 2], h3 = hist[4 * t + 3];
    int psum = h0 + h1 + h2 + h3;
    int incl = psum;
#pragma unroll
    for (int off = 1; off < 64; off <<= 1) {
        int v = __shfl_up(incl, off);
        if (lane >= off) incl += v;
    }
    if (lane == 63) wsum[w] = incl;
    __syncthreads();
    {
        int woff = 0;
#pragma unroll
        for (int k = 0; k < 3; ++k) woff += (k < w) ? wsum[k] : 0;
        int e0 = incl - psum + woff;
        int e1 = e0 + h0, e2 = e1 + h1, e3 = e2 + h2;
        istart[4 * t] = e0;     cnt[4 * t] = (float)e0;
        istart[4 * t + 1] = e1; cnt[4 * t + 1] = (float)e1;
        istart[4 * t + 2] = e2; cnt[4 * t + 2] = (float)e2;
        istart[4 * t + 3] = e3; cnt[4 * t + 3] = (float)e3;
        if (t == NTHREADS - 1) { istart[CELLS] = K_CENTERS; cnt[CELLS] = (float)K_CENTERS; }
    }
    __syncthreads();

    // ---- step 4: scatter (unordered within bucket) ----
    {
        int p0 = istart[b0] + atomicAdd(&ioff[b0], 1);
        sp[p0] = make_float2(cv0, (float)t);
        int p1 = istart[b1] + atomicAdd(&ioff[b1], 1);
        sp[p1] = make_float2(cv1, (float)(t + 256));
    }
    __syncthreads();

    // ---- step 5: per-bucket insertion sort (strict total order (value,idx)) ----
#pragma unroll
    for (int bb = 0; bb < 4; ++bb) {
        int b = 4 * t + bb;
        int s0 = istart[b], s1 = istart[b + 1];
        for (int i = s0 + 1; i < s1; ++i) {
            float2 key = sp[i];
            int j = i - 1;
            while (j >= s0 && pl_less(key, sp[j])) { sp[j + 1] = sp[j]; --j; }
            sp[j + 1] = key;
        }
    }
    __syncthreads();

    // ---- step 6: padded value array (bank-conflict-free segment reads) ----
    vals[t + (t >> 6)] = sp[t].x;
    {
        int t2 = t + 256;
        vals[t2 + (t2 >> 6)] = sp[t2].x;
    }
    __syncthreads();

    // ---- step 7: Chebyshev point values fp[p], 32 points x 8 segs of 64 ----
    {
        int p = t >> 3, s8 = t & 7;
        float xp = XC * __cosf((float)p * (PI_F / 31.0f));
        float ww = 0.f, wc = 0.f;
        int k0 = s8 * 64;
#pragma unroll 8
        for (int q = 0; q < 64; ++q) {
            int k = k0 + q;
            float cvq = vals[k + (k >> 6)];
            float d = xp - cvq;
            float e = __expf(-d * d);              // SIGMA = 1
            ww += e;
            wc = fmaf(e, cvq, wc);
        }
        ww += __shfl_xor(ww, 1); wc += __shfl_xor(wc, 1);
        ww += __shfl_xor(ww, 2); wc += __shfl_xor(wc, 2);
        ww += __shfl_xor(ww, 4); wc += __shfl_xor(wc, 4);
        if (s8 == 0) fp[p] = wc / ww;
    }
    __syncthreads();

    // ---- step 8: DCT-I coefficients (32 threads, incremental angle) ----
    if (t < CHEB_N) {
        int j = t;
        float acc = 0.f;
        int m = 0;
#pragma unroll
        for (int p = 0; p < CHEB_N; ++p) {
            float wgt = (p == 0 || p == CHEB_N - 1) ? 0.5f : 1.0f;
            acc = fmaf(wgt * fp[p], __cosf((float)m * (PI_F / 31.0f)), acc);
            m += j; if (m >= 62) m -= 62;          // angle stays in [0, 2pi)
        }
        float aj = acc * (2.0f / 31.0f);
        if (j == 0 || j == CHEB_N - 1) aj *= 0.5f; // fold sum'' convention
        cf[j] = aj;
    }
    __syncthreads();

    // ---- phase 2: 2 elements/thread ----
    float xs[2] = {xv.x, xv.y};
    float zb[2], so[2], sy[2];

    float y[2], y2[2], bA[2], bB[2];
#pragma unroll
    for (int e = 0; e < 2; ++e) {
        y[e] = fminf(fmaxf(xs[e] * (1.0f / XC), -1.0f), 1.0f);
        y2[e] = 2.0f * y[e];
        bA[e] = 0.f; bB[e] = 0.f;
    }
#pragma unroll
    for (int k = CHEB_N - 1; k >= 1; --k) {
        float ck = cf[k];                           // static addr: loads hoist
#pragma unroll
        for (int e = 0; e < 2; ++e) {
            float bb = fmaf(y2[e], bA[e], ck - bB[e]);
            bB[e] = bA[e]; bA[e] = bb;
        }
    }
    {
        float c0 = cf[0];
#pragma unroll
        for (int e = 0; e < 2; ++e) so[e] = fmaf(y[e], bA[e], c0 - bB[e]);
    }

#pragma unroll
    for (int e = 0; e < 2; ++e) {
        float x = xs[e];
        int n = min(max((int)((x + CLIM) * invstep), 0), CELLS - 1);
        int jlo = max((int)cnt[n] - 3, 0);
        int jhi = min((int)cnt[n + 1] + 2, K_CENTERS - 1);
        float bd2 = 3.4e38f;
        float bfo = 1.0e9f;       // original index as float (exact for <512)
        float bc = 0.f;
        for (int j = jlo; j <= jhi; ++j) {
            float2 P = sp[j];
            float d = x - P.x;        // same rounding as reference
            float d2 = d * d;         // same rounding as reference
            bool better = (d2 < bd2) || ((d2 == bd2) && (P.y < bfo));
            if (better) { bd2 = d2; bfo = P.y; bc = P.x; }
        }
        zb[e] = bc;                   // zbar forward value == hardout
        sy[e] = bfo;
    }

    *reinterpret_cast<float2*>(out + base)         = make_float2(zb[0], zb[1]);
    *reinterpret_cast<float2*>(out + N + base)     = make_float2(so[0], so[1]);
    *reinterpret_cast<float2*>(out + 2 * N + base) = make_float2(zb[0], zb[1]);
    *reinterpret_cast<float2*>(out + 3 * N + base) = make_float2(sy[0], sy[1]);
}

extern "C" void kernel_launch(void* const* d_in, const int* in_sizes, int n_in,
                              void* d_out, int out_size, void* d_ws, size_t ws_size,
                              hipStream_t stream) {
    const float* data    = (const float*)d_in[0];
    const float* centers = (const float*)d_in[1];
    float* out = (float*)d_out;
    int N = in_sizes[0];   // 524288 == 1024 * 256 * 2

    int blocks = N / (2 * NTHREADS);   // 1024
    fused_k<<<blocks, NTHREADS, 0, stream>>>(data, centers, out, N);
}

// Round 10
// 16.813 us; speedup vs baseline: 2.2795x; 1.0550x over previous
//
#include <hip/hip_runtime.h>
#include <math.h>

#define K_CENTERS 512
#define NTHREADS 256
#define CELLS 1024
#define CLIM 1.002f
#define CHEB_N 32                  /* points; degree 31 */
#define XC 5.5f                    /* Chebyshev domain [-XC, XC] */
#define PI_F 3.14159265358979f

__device__ __forceinline__ bool pl_less(float2 A, float2 B) {
    return (A.x < B.x) || (A.x == B.x && A.y < B.y);
}

// Single dispatch, zero cross-block communication. 1024 blocks x 256 threads
// (4 blocks/CU). Setup per block (~9 barriers, 14.6 KB LDS):
//  - counting sort of 512 (center,origIdx) pairs: one int array `ha` serves as
//    histogram -> bucket-start -> scatter cursor (atomicAdd returns position);
//    float cnt[] keeps the prefix sums, which double as the per-cell
//    insertion-count table for phase 2. Per-bucket insertion sort (buckets
//    avg 0.5 elems) gives strict (value, origIdx) order.
//  - degree-31 Chebyshev model of softout(x) on [-XC,XC]: 32 points x 8
//    lanes eval exact softmax-mean; DCT-I parallelized over all 256 threads
//    (32 coeffs x 8 lanes, shfl reduce) - no serial tail.
// Phase 2 (2 elems/thread): fully-unrolled Clenshaw softout; exact
// f32-faithful argmin via candidate scan of sorted neighbors (reference
// d=x-c, d2=d*d rounding, first-min tie-break on original index).
// Outputs (concat): zbar(=hardout), softout, hardout, symbols(as float).
__global__ __launch_bounds__(NTHREADS, 4) void fused_k(const float* __restrict__ data,
                                                       const float* __restrict__ centers,
                                                       float* __restrict__ out, int N) {
    __shared__ float2 sp[K_CENTERS];       // sorted {value, (float)origIdx}
    __shared__ float  vals[K_CENTERS + 8]; // sorted values, padded idx k+(k>>6)
    __shared__ float  cnt[CELLS + 1];      // bucket starts / insertion counts
    __shared__ int    ha[CELLS];           // hist -> starts -> scatter cursors
    __shared__ int    wsum[4];
    __shared__ float  fp[CHEB_N];          // softout at cheb points
    __shared__ float  cf[CHEB_N];          // cheb coeffs (ends pre-halved)
    int t = threadIdx.x;
    int lane = t & 63, w = t >> 6;         // 4 waves

    int base = (blockIdx.x * NTHREADS + t) * 2;   // exact fit: no bounds checks
    float2 xv = *reinterpret_cast<const float2*>(data + base);  // prefetch under setup

    const float invstep = (float)CELLS / (2.0f * CLIM);

    // ---- step 1: zero ha, load 2 centers ----
    ha[t] = 0; ha[t + 256] = 0; ha[t + 512] = 0; ha[t + 768] = 0;
    float cv0 = centers[t], cv1 = centers[t + 256];
    int b0 = min(max((int)((cv0 + CLIM) * invstep), 0), CELLS - 1);
    int b1 = min(max((int)((cv1 + CLIM) * invstep), 0), CELLS - 1);
    __syncthreads();

    // ---- step 2: histogram ----
    atomicAdd(&ha[b0], 1);
    atomicAdd(&ha[b1], 1);
    __syncthreads();

    // ---- step 3: prefix scan over 1024 buckets (4 per thread) ----
    int h0 = ha[4 * t], h1 = ha[4 * t + 1], h2 = ha[4 * t + 2], h3 = ha[4 * t + 3];
    int psum = h0 + h1 + h2 + h3;
    int incl = psum;
#pragma unroll
    for (int off = 1; off < 64; off <<= 1) {
        int v = __shfl_up(incl, off);
        if (lane >= off) incl += v;
    }
    if (lane == 63) wsum[w] = incl;
    __syncthreads();
    {
        int woff = 0;
        if (w > 0) woff += wsum[0];
        if (w > 1) woff += wsum[1];
        if (w > 2) woff += wsum[2];
        int e0 = incl - psum + woff;
        int e1 = e0 + h0, e2 = e1 + h1, e3 = e2 + h2;
        cnt[4 * t] = (float)e0;     ha[4 * t] = e0;
        cnt[4 * t + 1] = (float)e1; ha[4 * t + 1] = e1;
        cnt[4 * t + 2] = (float)e2; ha[4 * t + 2] = e2;
        cnt[4 * t + 3] = (float)e3; ha[4 * t + 3] = e3;
        if (t == NTHREADS - 1) cnt[CELLS] = (float)K_CENTERS;
    }
    __syncthreads();

    // ---- step 4: scatter (cursor = ha, post-increment gives position) ----
    {
        int p0 = atomicAdd(&ha[b0], 1);
        sp[p0] = make_float2(cv0, (float)t);
        int p1 = atomicAdd(&ha[b1], 1);
        sp[p1] = make_float2(cv1, (float)(t + 256));
    }
    __syncthreads();

    // ---- step 5: per-bucket insertion sort (bounds from cnt[]) ----
#pragma unroll
    for (int bb = 0; bb < 4; ++bb) {
        int b = 4 * t + bb;
        int s0 = (int)cnt[b], s1 = (int)cnt[b + 1];
        for (int i = s0 + 1; i < s1; ++i) {
            float2 key = sp[i];
            int j = i - 1;
            while (j >= s0 && pl_less(key, sp[j])) { sp[j + 1] = sp[j]; --j; }
            sp[j + 1] = key;
        }
    }
    __syncthreads();

    // ---- step 6: padded value array (bank-conflict-free segment reads) ----
    vals[t + (t >> 6)] = sp[t].x;
    {
        int t2 = t + 256;
        vals[t2 + (t2 >> 6)] = sp[t2].x;
    }
    __syncthreads();

    // ---- step 7: Chebyshev point values fp[p], 32 points x 8 lanes of 64 ----
    {
        int p = t >> 3, s8 = t & 7;
        float xp = XC * __cosf((float)p * (PI_F / 31.0f));
        float ww = 0.f, wc = 0.f;
        int k0 = s8 * 64;
#pragma unroll 8
        for (int q = 0; q < 64; ++q) {
            int k = k0 + q;
            float cvq = vals[k + (k >> 6)];
            float d = xp - cvq;
            float e = __expf(-d * d);              // SIGMA = 1
            ww += e;
            wc = fmaf(e, cvq, wc);
        }
        ww += __shfl_xor(ww, 1); wc += __shfl_xor(wc, 1);
        ww += __shfl_xor(ww, 2); wc += __shfl_xor(wc, 2);
        ww += __shfl_xor(ww, 4); wc += __shfl_xor(wc, 4);
        if (s8 == 0) fp[p] = wc / ww;
    }
    __syncthreads();

    // ---- step 8: DCT-I, parallel: 32 coeffs x 8 lanes (4 terms each) ----
    {
        int j = t >> 3, s8 = t & 7;
        int p0 = s8 * 4;
        int m = (j * p0) % 62;                     // angle index mod 2*pi
        float acc = 0.f;
#pragma unroll
        for (int q = 0; q < 4; ++q) {
            int p = p0 + q;
            float wgt = (p == 0 || p == CHEB_N - 1) ? 0.5f : 1.0f;
            acc = fmaf(wgt * fp[p], __cosf((float)m * (PI_F / 31.0f)), acc);
            m += j; if (m >= 62) m -= 62;
        }
        acc += __shfl_xor(acc, 1);
        acc += __shfl_xor(acc, 2);
        acc += __shfl_xor(acc, 4);
        if (s8 == 0) {
            float aj = acc * (2.0f / 31.0f);
            if (j == 0 || j == CHEB_N - 1) aj *= 0.5f;  // fold sum'' convention
            cf[j] = aj;
        }
    }
    __syncthreads();

    // ---- phase 2: 2 elements/thread ----
    float xs[2] = {xv.x, xv.y};
    float zb[2], so[2], sy[2];

    float y[2], y2[2], bA[2], bB[2];
#pragma unroll
    for (int e = 0; e < 2; ++e) {
        y[e] = fminf(fmaxf(xs[e] * (1.0f / XC), -1.0f), 1.0f);
        y2[e] = 2.0f * y[e];
        bA[e] = 0.f; bB[e] = 0.f;
    }
#pragma unroll
    for (int k = CHEB_N - 1; k >= 1; --k) {
        float ck = cf[k];                           // static addr: loads hoist
#pragma unroll
        for (int e = 0; e < 2; ++e) {
            float bb = fmaf(y2[e], bA[e], ck - bB[e]);
            bB[e] = bA[e]; bA[e] = bb;
        }
    }
    {
        float c0 = cf[0];
#pragma unroll
        for (int e = 0; e < 2; ++e) so[e] = fmaf(y[e], bA[e], c0 - bB[e]);
    }

#pragma unroll
    for (int e = 0; e < 2; ++e) {
        float x = xs[e];
        int n = min(max((int)((x + CLIM) * invstep), 0), CELLS - 1);
        int jlo = max((int)cnt[n] - 3, 0);
        int jhi = min((int)cnt[n + 1] + 2, K_CENTERS - 1);
        float bd2 = 3.4e38f;
        float bfo = 1.0e9f;       // original index as float (exact for <512)
        float bc = 0.f;
        for (int j = jlo; j <= jhi; ++j) {
            float2 P = sp[j];
            float d = x - P.x;        // same rounding as reference
            float d2 = d * d;         // same rounding as reference
            bool better = (d2 < bd2) || ((d2 == bd2) && (P.y < bfo));
            if (better) { bd2 = d2; bfo = P.y; bc = P.x; }
        }
        zb[e] = bc;                   // zbar forward value == hardout
        sy[e] = bfo;
    }

    *reinterpret_cast<float2*>(out + base)         = make_float2(zb[0], zb[1]);
    *reinterpret_cast<float2*>(out + N + base)     = make_float2(so[0], so[1]);
    *reinterpret_cast<float2*>(out + 2 * N + base) = make_float2(zb[0], zb[1]);
    *reinterpret_cast<float2*>(out + 3 * N + base) = make_float2(sy[0], sy[1]);
}

extern "C" void kernel_launch(void* const* d_in, const int* in_sizes, int n_in,
                              void* d_out, int out_size, void* d_ws, size_t ws_size,
                              hipStream_t stream) {
    const float* data    = (const float*)d_in[0];
    const float* centers = (const float*)d_in[1];
    float* out = (float*)d_out;
    int N = in_sizes[0];   // 524288 == 1024 * 256 * 2

    int blocks = N / (2 * NTHREADS);   // 1024
    fused_k<<<blocks, NTHREADS, 0, stream>>>(data, centers, out, N);
}